// Round 1
// baseline (3114.350 us; speedup 1.0000x reference)
//
#include <hip/hip_runtime.h>
#include <hip/hip_bf16.h>

#define N_NODES 100000
#define N_EDGES 1600000
#define IN_DIM  256
#define OUT_DIM 128

// ---------------- GEMM: H[N, 128] = X[N, 256] @ W[256, 128] (f32) ----------
// Block = 256 threads = 2 row-groups x 128 cols. Each thread computes 8 rows
// for its column -> 16 rows per block. X loads broadcast within a row-group
// (L1-served), W loads coalesced across the 128 cols (L2-hot, W = 128 KB).
__global__ __launch_bounds__(256) void gemm_xw(const float* __restrict__ X,
                                               const float* __restrict__ W,
                                               float* __restrict__ H) {
    const int col  = threadIdx.x & 127;
    const int rg   = threadIdx.x >> 7;             // 0..1
    const int row0 = blockIdx.x * 16 + rg * 8;

    float acc[8];
#pragma unroll
    for (int i = 0; i < 8; ++i) acc[i] = 0.0f;

    const float* x = X + (size_t)row0 * IN_DIM;

    for (int k = 0; k < IN_DIM; k += 4) {
        const float w0 = W[(k + 0) * OUT_DIM + col];
        const float w1 = W[(k + 1) * OUT_DIM + col];
        const float w2 = W[(k + 2) * OUT_DIM + col];
        const float w3 = W[(k + 3) * OUT_DIM + col];
#pragma unroll
        for (int i = 0; i < 8; ++i) {
            const float4 xi = *reinterpret_cast<const float4*>(x + i * IN_DIM + k);
            acc[i] = fmaf(xi.x, w0, acc[i]);
            acc[i] = fmaf(xi.y, w1, acc[i]);
            acc[i] = fmaf(xi.z, w2, acc[i]);
            acc[i] = fmaf(xi.w, w3, acc[i]);
        }
    }

#pragma unroll
    for (int i = 0; i < 8; ++i)
        H[(size_t)(row0 + i) * OUT_DIM + col] = acc[i];
}

// ---------------- SpMM scatter: out[dst] += val * H[src] -------------------
// 32 lanes per edge, each lane covers 4 consecutive cols via float4 gather,
// then 4 scalar atomicAdds. 8 edges per 256-thread block.
__global__ __launch_bounds__(256) void spmm_scatter(const float4* __restrict__ H4,
                                                    const int* __restrict__ esrc,
                                                    const int* __restrict__ edst,
                                                    const float* __restrict__ eval,
                                                    float* __restrict__ out) {
    const int lane = threadIdx.x & 31;   // 0..31  (covers 4 cols each)
    const int slot = threadIdx.x >> 5;   // 0..7
    const int e    = blockIdx.x * 8 + slot;
    if (e >= N_EDGES) return;

    const int   s = esrc[e];
    const int   d = edst[e];
    const float v = eval[e];

    const float4 h = H4[(size_t)s * 32 + lane];
    float* o = out + (size_t)d * OUT_DIM + lane * 4;
    atomicAdd(o + 0, v * h.x);
    atomicAdd(o + 1, v * h.y);
    atomicAdd(o + 2, v * h.z);
    atomicAdd(o + 3, v * h.w);
}

// ---------------- ReLU in place --------------------------------------------
__global__ __launch_bounds__(256) void relu_inplace(float4* __restrict__ out, int n4) {
    const int i = blockIdx.x * 256 + threadIdx.x;
    if (i < n4) {
        float4 v = out[i];
        v.x = fmaxf(v.x, 0.0f);
        v.y = fmaxf(v.y, 0.0f);
        v.z = fmaxf(v.z, 0.0f);
        v.w = fmaxf(v.w, 0.0f);
        out[i] = v;
    }
}

extern "C" void kernel_launch(void* const* d_in, const int* in_sizes, int n_in,
                              void* d_out, int out_size, void* d_ws, size_t ws_size,
                              hipStream_t stream) {
    const float* X    = (const float*)d_in[0];   // [N_NODES, IN_DIM]
    const float* W    = (const float*)d_in[1];   // [IN_DIM, OUT_DIM]
    const int*   esrc = (const int*)d_in[2];     // [N_EDGES]
    const int*   edst = (const int*)d_in[3];     // [N_EDGES]
    const float* eval = (const float*)d_in[4];   // [N_EDGES]
    float*       out  = (float*)d_out;           // [N_NODES, OUT_DIM]

    float* H = (float*)d_ws;                     // [N_NODES, OUT_DIM] scratch (51.2 MB)

    // Zero the output accumulator (atomics accumulate into it).
    hipMemsetAsync(d_out, 0, (size_t)out_size * sizeof(float), stream);

    // 1) H = X @ W
    gemm_xw<<<N_NODES / 16, 256, 0, stream>>>(X, W, H);

    // 2) out[dst] += val * H[src]
    const int spmm_blocks = (N_EDGES + 7) / 8;
    spmm_scatter<<<spmm_blocks, 256, 0, stream>>>((const float4*)H, esrc, edst, eval, out);

    // 3) ReLU
    const int n4 = (N_NODES * OUT_DIM) / 4;
    relu_inplace<<<(n4 + 255) / 256, 256, 0, stream>>>((float4*)out, n4);
}

// Round 2
// 810.659 us; speedup vs baseline: 3.8417x; 3.8417x over previous
//
#include <hip/hip_runtime.h>
#include <hip/hip_bf16.h>

#define N_NODES 100000
#define N_EDGES 1600000
#define IN_DIM  256
#define OUT_DIM 128

// ---------------- GEMM: H[N, 128] = X[N, 256] @ W[256, 128] (f32) ----------
__global__ __launch_bounds__(256) void gemm_xw(const float* __restrict__ X,
                                               const float* __restrict__ W,
                                               float* __restrict__ H) {
    const int col  = threadIdx.x & 127;
    const int rg   = threadIdx.x >> 7;             // 0..1
    const int row0 = blockIdx.x * 16 + rg * 8;

    float acc[8];
#pragma unroll
    for (int i = 0; i < 8; ++i) acc[i] = 0.0f;

    const float* x = X + (size_t)row0 * IN_DIM;

    for (int k = 0; k < IN_DIM; k += 4) {
        const float w0 = W[(k + 0) * OUT_DIM + col];
        const float w1 = W[(k + 1) * OUT_DIM + col];
        const float w2 = W[(k + 2) * OUT_DIM + col];
        const float w3 = W[(k + 3) * OUT_DIM + col];
#pragma unroll
        for (int i = 0; i < 8; ++i) {
            const float4 xi = *reinterpret_cast<const float4*>(x + i * IN_DIM + k);
            acc[i] = fmaf(xi.x, w0, acc[i]);
            acc[i] = fmaf(xi.y, w1, acc[i]);
            acc[i] = fmaf(xi.z, w2, acc[i]);
            acc[i] = fmaf(xi.w, w3, acc[i]);
        }
    }

#pragma unroll
    for (int i = 0; i < 8; ++i)
        H[(size_t)(row0 + i) * OUT_DIM + col] = acc[i];
}

// ---------------- CSR build: histogram -> scan -> scatter ------------------
__global__ __launch_bounds__(256) void hist_dst(const int* __restrict__ edst,
                                                int* __restrict__ offsets) {
    const int i = blockIdx.x * 256 + threadIdx.x;
    if (i < N_EDGES) atomicAdd(&offsets[edst[i] + 1], 1);
}

// Single-block inclusive scan over a[0..n-1] (n ~= 100001), shfl-based.
__global__ __launch_bounds__(1024) void scan_offsets(int* __restrict__ a, int n) {
    __shared__ int wsum[16];
    __shared__ int carry_s;
    const int tid = threadIdx.x, lane = tid & 63, wid = tid >> 6;
    if (tid == 0) carry_s = 0;
    __syncthreads();
    for (int base = 0; base < n; base += 1024) {
        const int i = base + tid;
        int sv = (i < n) ? a[i] : 0;
#pragma unroll
        for (int d = 1; d < 64; d <<= 1) {
            const int t = __shfl_up(sv, d, 64);
            if (lane >= d) sv += t;
        }
        if (lane == 63) wsum[wid] = sv;
        __syncthreads();
        if (wid == 0) {
            int w = (lane < 16) ? wsum[lane] : 0;
#pragma unroll
            for (int d = 1; d < 16; d <<= 1) {
                const int t = __shfl_up(w, d, 64);
                if (lane >= d) w += t;
            }
            if (lane < 16) wsum[lane] = w;
        }
        __syncthreads();
        const int wbase = (wid > 0) ? wsum[wid - 1] : 0;
        const int inc = sv + wbase + carry_s;
        if (i < n) a[i] = inc;
        const int total = wsum[15] + carry_s;   // read carry_s before overwrite
        __syncthreads();
        if (tid == 0) carry_s = total;
        __syncthreads();
    }
}

__global__ __launch_bounds__(256) void copy_cursor(const int* __restrict__ offsets,
                                                   int* __restrict__ cursor) {
    const int i = blockIdx.x * 256 + threadIdx.x;
    if (i < N_NODES) cursor[i] = offsets[i];
}

__global__ __launch_bounds__(256) void build_csr(const int* __restrict__ esrc,
                                                 const int* __restrict__ edst,
                                                 const float* __restrict__ eval,
                                                 int* __restrict__ cursor,
                                                 int* __restrict__ ssrc,
                                                 float* __restrict__ sval) {
    const int e = blockIdx.x * 256 + threadIdx.x;
    if (e < N_EDGES) {
        const int d = edst[e];
        const int p = atomicAdd(&cursor[d], 1);
        ssrc[p] = esrc[e];
        sval[p] = eval[e];
    }
}

// ---------------- SpMM pull: one wave per dst node, ReLU fused -------------
__global__ __launch_bounds__(256) void spmm_pull(const float* __restrict__ H,
                                                 const int* __restrict__ offsets,
                                                 const int* __restrict__ ssrc,
                                                 const float* __restrict__ sval,
                                                 float* __restrict__ out) {
    const int node = (blockIdx.x * 256 + threadIdx.x) >> 6;
    const int lane = threadIdx.x & 63;
    if (node >= N_NODES) return;

    const int beg = offsets[node];
    const int end = offsets[node + 1];

    float ax = 0.0f, ay = 0.0f;
    int e = beg;
    for (; e + 1 < end; e += 2) {                    // 2-edge unroll for MLP/ILP
        const int   s0 = ssrc[e],     s1 = ssrc[e + 1];
        const float v0 = sval[e],     v1 = sval[e + 1];
        const float2 h0 = *reinterpret_cast<const float2*>(H + (size_t)s0 * OUT_DIM + lane * 2);
        const float2 h1 = *reinterpret_cast<const float2*>(H + (size_t)s1 * OUT_DIM + lane * 2);
        ax = fmaf(v0, h0.x, ax);  ay = fmaf(v0, h0.y, ay);
        ax = fmaf(v1, h1.x, ax);  ay = fmaf(v1, h1.y, ay);
    }
    if (e < end) {
        const int   s0 = ssrc[e];
        const float v0 = sval[e];
        const float2 h0 = *reinterpret_cast<const float2*>(H + (size_t)s0 * OUT_DIM + lane * 2);
        ax = fmaf(v0, h0.x, ax);  ay = fmaf(v0, h0.y, ay);
    }

    float2 r;
    r.x = fmaxf(ax, 0.0f);
    r.y = fmaxf(ay, 0.0f);
    *reinterpret_cast<float2*>(out + (size_t)node * OUT_DIM + lane * 2) = r;
}

// ---------------- Fallback (small ws): original atomic scatter -------------
__global__ __launch_bounds__(256) void spmm_scatter(const float4* __restrict__ H4,
                                                    const int* __restrict__ esrc,
                                                    const int* __restrict__ edst,
                                                    const float* __restrict__ eval,
                                                    float* __restrict__ out) {
    const int lane = threadIdx.x & 31;
    const int slot = threadIdx.x >> 5;
    const int e    = blockIdx.x * 8 + slot;
    if (e >= N_EDGES) return;
    const int   s = esrc[e];
    const int   d = edst[e];
    const float v = eval[e];
    const float4 h = H4[(size_t)s * 32 + lane];
    float* o = out + (size_t)d * OUT_DIM + lane * 4;
    atomicAdd(o + 0, v * h.x);
    atomicAdd(o + 1, v * h.y);
    atomicAdd(o + 2, v * h.z);
    atomicAdd(o + 3, v * h.w);
}

__global__ __launch_bounds__(256) void relu_inplace(float4* __restrict__ out, int n4) {
    const int i = blockIdx.x * 256 + threadIdx.x;
    if (i < n4) {
        float4 v = out[i];
        v.x = fmaxf(v.x, 0.0f); v.y = fmaxf(v.y, 0.0f);
        v.z = fmaxf(v.z, 0.0f); v.w = fmaxf(v.w, 0.0f);
        out[i] = v;
    }
}

extern "C" void kernel_launch(void* const* d_in, const int* in_sizes, int n_in,
                              void* d_out, int out_size, void* d_ws, size_t ws_size,
                              hipStream_t stream) {
    const float* X    = (const float*)d_in[0];   // [N_NODES, IN_DIM]
    const float* W    = (const float*)d_in[1];   // [IN_DIM, OUT_DIM]
    const int*   esrc = (const int*)d_in[2];     // [N_EDGES]
    const int*   edst = (const int*)d_in[3];     // [N_EDGES]
    const float* eval = (const float*)d_in[4];   // [N_EDGES]
    float*       out  = (float*)d_out;           // [N_NODES, OUT_DIM]

    // Workspace layout
    const size_t H_BYTES   = (size_t)N_NODES * OUT_DIM * sizeof(float);   // 51.2 MB
    const size_t OFF_BYTES = ((size_t)(N_NODES + 1) * sizeof(int) + 127) & ~(size_t)127;
    const size_t CUR_BYTES = ((size_t)N_NODES * sizeof(int) + 127) & ~(size_t)127;
    const size_t SRC_BYTES = (size_t)N_EDGES * sizeof(int);
    const size_t VAL_BYTES = (size_t)N_EDGES * sizeof(float);
    const size_t NEED = H_BYTES + OFF_BYTES + CUR_BYTES + SRC_BYTES + VAL_BYTES;

    char* ws = (char*)d_ws;
    float* H       = (float*)ws;                  ws += H_BYTES;
    int*   offsets = (int*)ws;                    ws += OFF_BYTES;
    int*   cursor  = (int*)ws;                    ws += CUR_BYTES;
    int*   ssrc    = (int*)ws;                    ws += SRC_BYTES;
    float* sval    = (float*)ws;

    // 1) H = X @ W
    gemm_xw<<<N_NODES / 16, 256, 0, stream>>>(X, W, H);

    if (ws_size >= NEED) {
        // 2) Build CSR by destination
        hipMemsetAsync(offsets, 0, (size_t)(N_NODES + 1) * sizeof(int), stream);
        hist_dst<<<(N_EDGES + 255) / 256, 256, 0, stream>>>(edst, offsets);
        scan_offsets<<<1, 1024, 0, stream>>>(offsets, N_NODES + 1);
        copy_cursor<<<(N_NODES + 255) / 256, 256, 0, stream>>>(offsets, cursor);
        build_csr<<<(N_EDGES + 255) / 256, 256, 0, stream>>>(esrc, edst, eval,
                                                             cursor, ssrc, sval);
        // 3) Pull-SpMM + ReLU, one wave per node
        const int total_thr = N_NODES * 64;
        spmm_pull<<<(total_thr + 255) / 256, 256, 0, stream>>>(H, offsets, ssrc, sval, out);
    } else {
        // Fallback: atomic scatter path
        hipMemsetAsync(d_out, 0, (size_t)out_size * sizeof(float), stream);
        spmm_scatter<<<(N_EDGES + 7) / 8, 256, 0, stream>>>((const float4*)H, esrc, edst,
                                                            eval, out);
        const int n4 = (N_NODES * OUT_DIM) / 4;
        relu_inplace<<<(n4 + 255) / 256, 256, 0, stream>>>((float4*)out, n4);
    }
}

// Round 3
// 361.411 us; speedup vs baseline: 8.6172x; 2.2430x over previous
//
#include <hip/hip_runtime.h>
#include <hip/hip_bf16.h>

#define N_NODES 100000
#define N_EDGES 1600000
#define IN_DIM  256
#define OUT_DIM 128

typedef __attribute__((ext_vector_type(8))) short bf16x8;
typedef __attribute__((ext_vector_type(4))) float f32x4;

__device__ __forceinline__ ushort f2bf(float f) {
    union { float f; unsigned u; } v; v.f = f;
    unsigned r = v.u + 0x7FFF + ((v.u >> 16) & 1);   // RNE
    return (ushort)(r >> 16);
}
__device__ __forceinline__ float bflo(unsigned u) {
    union { unsigned u; float f; } v; v.u = u << 16; return v.f;
}
__device__ __forceinline__ float bfhi(unsigned u) {
    union { unsigned u; float f; } v; v.u = u & 0xFFFF0000u; return v.f;
}

// ---------------- Pack W[256,128] f32 -> bf16 fragment-major ---------------
// Wp[((kk*8 + n)*64 + l)*8 + j] = bf16( W[(kk*32 + (l>>4)*8 + j)*128 + n*16 + (l&15)] )
__global__ __launch_bounds__(256) void pack_w(const float* __restrict__ W,
                                              ushort* __restrict__ Wp) {
    const int t = blockIdx.x * 256 + threadIdx.x;
    if (t >= 4096) return;
    const int kk = t >> 9, n = (t >> 6) & 7, l = t & 63;
    const int kbase = kk * 32 + (l >> 4) * 8;
    const int col   = n * 16 + (l & 15);
    ushort* o = Wp + (size_t)t * 8;
#pragma unroll
    for (int j = 0; j < 8; ++j)
        o[j] = f2bf(W[(size_t)(kbase + j) * OUT_DIM + col]);
}

// ---------------- MFMA GEMM: H(bf16)[N,128] = bf16(X[N,256]) @ bf16(W) -----
// 4 waves/block, wave = 32 rows x 128 cols. A converted f32->bf16 in-register.
__global__ __launch_bounds__(256) void gemm_mfma(const float* __restrict__ X,
                                                 const bf16x8* __restrict__ Bp,
                                                 ushort* __restrict__ H) {
    const int lane = threadIdx.x & 63;
    const int wid  = threadIdx.x >> 6;               // 0..3
    const int row0 = blockIdx.x * 128 + wid * 32;
    const int rlo  = lane & 15;
    const int kseg = lane >> 4;                      // 0..3

    f32x4 acc[2][8] = {};

    int ra = row0 + rlo;       if (ra >= N_NODES) ra = N_NODES - 1;
    int rb = row0 + 16 + rlo;  if (rb >= N_NODES) rb = N_NODES - 1;
    const float* pa = X + (size_t)ra * IN_DIM + kseg * 8;
    const float* pb = X + (size_t)rb * IN_DIM + kseg * 8;

    for (int kk = 0; kk < 8; ++kk) {
        const float4 a0lo = *(const float4*)(pa + kk * 32);
        const float4 a0hi = *(const float4*)(pa + kk * 32 + 4);
        const float4 a1lo = *(const float4*)(pb + kk * 32);
        const float4 a1hi = *(const float4*)(pb + kk * 32 + 4);
        bf16x8 A0, A1;
        A0[0]=f2bf(a0lo.x); A0[1]=f2bf(a0lo.y); A0[2]=f2bf(a0lo.z); A0[3]=f2bf(a0lo.w);
        A0[4]=f2bf(a0hi.x); A0[5]=f2bf(a0hi.y); A0[6]=f2bf(a0hi.z); A0[7]=f2bf(a0hi.w);
        A1[0]=f2bf(a1lo.x); A1[1]=f2bf(a1lo.y); A1[2]=f2bf(a1lo.z); A1[3]=f2bf(a1lo.w);
        A1[4]=f2bf(a1hi.x); A1[5]=f2bf(a1hi.y); A1[6]=f2bf(a1hi.z); A1[7]=f2bf(a1hi.w);

        const bf16x8* bbase = Bp + (size_t)(kk * 8) * 64 + lane;
#pragma unroll
        for (int n = 0; n < 8; ++n) {
            const bf16x8 Bf = bbase[(size_t)n * 64];
            acc[0][n] = __builtin_amdgcn_mfma_f32_16x16x32_bf16(A0, Bf, acc[0][n], 0, 0, 0);
            acc[1][n] = __builtin_amdgcn_mfma_f32_16x16x32_bf16(A1, Bf, acc[1][n], 0, 0, 0);
        }
    }

    // C/D layout: col = n*16 + (lane&15), row = i*16 + (lane>>4)*4 + r
#pragma unroll
    for (int i = 0; i < 2; ++i) {
#pragma unroll
        for (int r = 0; r < 4; ++r) {
            const int row = row0 + i * 16 + kseg * 4 + r;
            if (row < N_NODES) {
#pragma unroll
                for (int n = 0; n < 8; ++n)
                    H[(size_t)row * OUT_DIM + n * 16 + rlo] = f2bf(acc[i][n][r]);
            }
        }
    }
}

// ---------------- CSR build ------------------------------------------------
__global__ __launch_bounds__(256) void hist_dst(const int* __restrict__ edst,
                                                int* __restrict__ offsets) {
    const int i = blockIdx.x * 256 + threadIdx.x;
    if (i < N_EDGES) atomicAdd(&offsets[edst[i] + 1], 1);
}

// 3-phase parallel scan over offsets[0..n-1], n = N_NODES+1, 25 blocks x 4096
#define SCAN_NBLK 25
__global__ __launch_bounds__(1024) void scan_phase1(int* __restrict__ a, int n,
                                                    int* __restrict__ bsum) {
    __shared__ int wsum[16];
    const int tid = threadIdx.x, lane = tid & 63, wid = tid >> 6;
    const int base = blockIdx.x * 4096 + tid * 4;
    int e0 = (base + 0 < n) ? a[base + 0] : 0;
    int e1 = (base + 1 < n) ? a[base + 1] : 0;
    int e2 = (base + 2 < n) ? a[base + 2] : 0;
    int e3 = (base + 3 < n) ? a[base + 3] : 0;
    const int p0 = e0, p1 = p0 + e1, p2 = p1 + e2, p3 = p2 + e3;
    const int ts = p3;
    int sv = ts;
#pragma unroll
    for (int d = 1; d < 64; d <<= 1) {
        const int t = __shfl_up(sv, d, 64);
        if (lane >= d) sv += t;
    }
    if (lane == 63) wsum[wid] = sv;
    __syncthreads();
    if (wid == 0 && lane < 16) {
        int w = wsum[lane];
#pragma unroll
        for (int d = 1; d < 16; d <<= 1) {
            const int t = __shfl_up(w, d, 64);
            if (lane >= d) w += t;
        }
        wsum[lane] = w;
    }
    __syncthreads();
    const int wexcl = (wid > 0) ? wsum[wid - 1] : 0;
    const int texcl = (sv - ts) + wexcl;
    if (base + 0 < n) a[base + 0] = texcl + p0;
    if (base + 1 < n) a[base + 1] = texcl + p1;
    if (base + 2 < n) a[base + 2] = texcl + p2;
    if (base + 3 < n) a[base + 3] = texcl + p3;
    if (tid == 0) bsum[blockIdx.x] = wsum[15];
}

__global__ __launch_bounds__(64) void scan_phase2(int* __restrict__ bsum, int nb) {
    const int lane = threadIdx.x;
    const int v = (lane < nb) ? bsum[lane] : 0;
    int sv = v;
#pragma unroll
    for (int d = 1; d < 64; d <<= 1) {
        const int t = __shfl_up(sv, d, 64);
        if (lane >= d) sv += t;
    }
    if (lane < nb) bsum[lane] = sv - v;    // exclusive
}

__global__ __launch_bounds__(1024) void scan_phase3(int* __restrict__ a, int n,
                                                    const int* __restrict__ bsum,
                                                    int* __restrict__ cursor) {
    const int base = blockIdx.x * 4096 + threadIdx.x * 4;
    const int add  = bsum[blockIdx.x];
#pragma unroll
    for (int j = 0; j < 4; ++j) {
        const int i = base + j;
        if (i < n) {
            const int v = a[i] + add;
            a[i] = v;
            if (i < N_NODES) cursor[i] = v;
        }
    }
}

__global__ __launch_bounds__(256) void build_csr(const int* __restrict__ esrc,
                                                 const int* __restrict__ edst,
                                                 const float* __restrict__ eval,
                                                 int* __restrict__ cursor,
                                                 int* __restrict__ ssrc,
                                                 float* __restrict__ sval) {
    const int e = blockIdx.x * 256 + threadIdx.x;
    if (e < N_EDGES) {
        const int d = edst[e];
        const int p = atomicAdd(&cursor[d], 1);
        ssrc[p] = esrc[e];
        sval[p] = eval[e];
    }
}

// ---------------- SpMM pull (bf16 H): one wave per dst node, ReLU fused ----
__global__ __launch_bounds__(256) void spmm_pull(const ushort* __restrict__ H,
                                                 const int* __restrict__ offsets,
                                                 const int* __restrict__ ssrc,
                                                 const float* __restrict__ sval,
                                                 float* __restrict__ out) {
    const int node = (blockIdx.x * 256 + threadIdx.x) >> 6;
    const int lane = threadIdx.x & 63;
    if (node >= N_NODES) return;

    const int beg = offsets[node];
    const int end = offsets[node + 1];

    float ax = 0.0f, ay = 0.0f;
    int e = beg;
    for (; e + 1 < end; e += 2) {
        const int   s0 = ssrc[e],   s1 = ssrc[e + 1];
        const float v0 = sval[e],   v1 = sval[e + 1];
        const unsigned h0 = *(const unsigned*)(H + (size_t)s0 * OUT_DIM + lane * 2);
        const unsigned h1 = *(const unsigned*)(H + (size_t)s1 * OUT_DIM + lane * 2);
        ax = fmaf(v0, bflo(h0), ax);  ay = fmaf(v0, bfhi(h0), ay);
        ax = fmaf(v1, bflo(h1), ax);  ay = fmaf(v1, bfhi(h1), ay);
    }
    if (e < end) {
        const int   s0 = ssrc[e];
        const float v0 = sval[e];
        const unsigned h0 = *(const unsigned*)(H + (size_t)s0 * OUT_DIM + lane * 2);
        ax = fmaf(v0, bflo(h0), ax);  ay = fmaf(v0, bfhi(h0), ay);
    }

    float2 r;
    r.x = fmaxf(ax, 0.0f);
    r.y = fmaxf(ay, 0.0f);
    *reinterpret_cast<float2*>(out + (size_t)node * OUT_DIM + lane * 2) = r;
}

extern "C" void kernel_launch(void* const* d_in, const int* in_sizes, int n_in,
                              void* d_out, int out_size, void* d_ws, size_t ws_size,
                              hipStream_t stream) {
    const float* X    = (const float*)d_in[0];   // [N_NODES, IN_DIM]
    const float* W    = (const float*)d_in[1];   // [IN_DIM, OUT_DIM]
    const int*   esrc = (const int*)d_in[2];     // [N_EDGES]
    const int*   edst = (const int*)d_in[3];     // [N_EDGES]
    const float* eval = (const float*)d_in[4];   // [N_EDGES]
    float*       out  = (float*)d_out;           // [N_NODES, OUT_DIM]

    // Workspace layout (~39 MB; harness provided >=65 MB in prior rounds)
    char* ws = (char*)d_ws;
    ushort* Hb     = (ushort*)ws;  ws += (size_t)N_NODES * OUT_DIM * sizeof(ushort);   // 25.6 MB
    ushort* Wp     = (ushort*)ws;  ws += (size_t)4096 * 8 * sizeof(ushort);            // 64 KB
    int*    offsets= (int*)ws;     ws += (((size_t)(N_NODES + 1) * 4 + 127) & ~(size_t)127);
    int*    bsum   = (int*)ws;     ws += 128;
    int*    cursor = (int*)ws;     ws += (((size_t)N_NODES * 4 + 127) & ~(size_t)127);
    int*    ssrc   = (int*)ws;     ws += (size_t)N_EDGES * sizeof(int);                // 6.4 MB
    float*  sval   = (float*)ws;

    // 1) Pack W to bf16 fragment-major; GEMM H = bf16(X) @ bf16(W)
    pack_w<<<16, 256, 0, stream>>>(W, Wp);
    gemm_mfma<<<(N_NODES + 127) / 128, 256, 0, stream>>>(X, (const bf16x8*)Wp, Hb);

    // 2) CSR build (dst-sorted)
    hipMemsetAsync(offsets, 0, (size_t)(N_NODES + 1) * sizeof(int), stream);
    hist_dst<<<(N_EDGES + 255) / 256, 256, 0, stream>>>(edst, offsets);
    scan_phase1<<<SCAN_NBLK, 1024, 0, stream>>>(offsets, N_NODES + 1, bsum);
    scan_phase2<<<1, 64, 0, stream>>>(bsum, SCAN_NBLK);
    scan_phase3<<<SCAN_NBLK, 1024, 0, stream>>>(offsets, N_NODES + 1, bsum, cursor);
    build_csr<<<(N_EDGES + 255) / 256, 256, 0, stream>>>(esrc, edst, eval,
                                                         cursor, ssrc, sval);

    // 3) Pull-SpMM + ReLU, one wave per node
    spmm_pull<<<(N_NODES * 64 + 255) / 256, 256, 0, stream>>>(Hb, offsets, ssrc, sval, out);
}

// Round 4
// 287.177 us; speedup vs baseline: 10.8447x; 1.2585x over previous
//
#include <hip/hip_runtime.h>
#include <hip/hip_bf16.h>

#define N_NODES 100000
#define N_EDGES 1600000
#define IN_DIM  256
#define OUT_DIM 128

#define GEMM_BLOCKS ((N_NODES + 127) / 128)        // 782
#define HIST_BLOCKS (N_EDGES / 256)                // 6250

typedef __attribute__((ext_vector_type(8))) short bf16x8;
typedef __attribute__((ext_vector_type(4))) float f32x4;

__device__ __forceinline__ ushort f2bf(float f) {
    union { float f; unsigned u; } v; v.f = f;
    unsigned r = v.u + 0x7FFF + ((v.u >> 16) & 1);   // RNE
    return (ushort)(r >> 16);
}
__device__ __forceinline__ float bflo(unsigned u) {
    union { unsigned u; float f; } v; v.u = u << 16; return v.f;
}
__device__ __forceinline__ float bfhi(unsigned u) {
    union { unsigned u; float f; } v; v.u = u & 0xFFFF0000u; return v.f;
}

// ---------------- Pack W[256,128] f32 -> bf16 fragment-major ---------------
// Wp[((kk*8 + n)*64 + l)*8 + j] = bf16( W[(kk*32 + (l>>4)*8 + j)*128 + n*16 + (l&15)] )
__global__ __launch_bounds__(256) void pack_w(const float* __restrict__ W,
                                              ushort* __restrict__ Wp) {
    const int t = blockIdx.x * 256 + threadIdx.x;
    if (t >= 4096) return;
    const int kk = t >> 9, n = (t >> 6) & 7, l = t & 63;
    const int kbase = kk * 32 + (l >> 4) * 8;
    const int col   = n * 16 + (l & 15);
    ushort* o = Wp + (size_t)t * 8;
#pragma unroll
    for (int j = 0; j < 8; ++j)
        o[j] = f2bf(W[(size_t)(kbase + j) * OUT_DIM + col]);
}

// ---------------- Fused: MFMA GEMM (blocks < GEMM_BLOCKS) + dst histogram --
__global__ __launch_bounds__(256) void gemm_hist(const float* __restrict__ X,
                                                 const bf16x8* __restrict__ Bp,
                                                 ushort* __restrict__ H,
                                                 const int* __restrict__ edst,
                                                 int* __restrict__ offsets) {
    if (blockIdx.x >= GEMM_BLOCKS) {
        // ---- histogram part ----
        const int i = (blockIdx.x - GEMM_BLOCKS) * 256 + threadIdx.x;
        if (i < N_EDGES) atomicAdd(&offsets[edst[i] + 1], 1);
        return;
    }

    // ---- GEMM part: 4 waves/block, wave = 32 rows x 128 cols ----
    const int lane = threadIdx.x & 63;
    const int wid  = threadIdx.x >> 6;               // 0..3
    const int row0 = blockIdx.x * 128 + wid * 32;
    const int rlo  = lane & 15;
    const int kseg = lane >> 4;                      // 0..3

    f32x4 acc[2][8] = {};

    int ra = row0 + rlo;       if (ra >= N_NODES) ra = N_NODES - 1;
    int rb = row0 + 16 + rlo;  if (rb >= N_NODES) rb = N_NODES - 1;
    const float* pa = X + (size_t)ra * IN_DIM + kseg * 8;
    const float* pb = X + (size_t)rb * IN_DIM + kseg * 8;

    for (int kk = 0; kk < 8; ++kk) {
        const float4 a0lo = *(const float4*)(pa + kk * 32);
        const float4 a0hi = *(const float4*)(pa + kk * 32 + 4);
        const float4 a1lo = *(const float4*)(pb + kk * 32);
        const float4 a1hi = *(const float4*)(pb + kk * 32 + 4);
        bf16x8 A0, A1;
        A0[0]=f2bf(a0lo.x); A0[1]=f2bf(a0lo.y); A0[2]=f2bf(a0lo.z); A0[3]=f2bf(a0lo.w);
        A0[4]=f2bf(a0hi.x); A0[5]=f2bf(a0hi.y); A0[6]=f2bf(a0hi.z); A0[7]=f2bf(a0hi.w);
        A1[0]=f2bf(a1lo.x); A1[1]=f2bf(a1lo.y); A1[2]=f2bf(a1lo.z); A1[3]=f2bf(a1lo.w);
        A1[4]=f2bf(a1hi.x); A1[5]=f2bf(a1hi.y); A1[6]=f2bf(a1hi.z); A1[7]=f2bf(a1hi.w);

        const bf16x8* bbase = Bp + (size_t)(kk * 8) * 64 + lane;
#pragma unroll
        for (int n = 0; n < 8; ++n) {
            const bf16x8 Bf = bbase[(size_t)n * 64];
            acc[0][n] = __builtin_amdgcn_mfma_f32_16x16x32_bf16(A0, Bf, acc[0][n], 0, 0, 0);
            acc[1][n] = __builtin_amdgcn_mfma_f32_16x16x32_bf16(A1, Bf, acc[1][n], 0, 0, 0);
        }
    }

    // C/D layout: col = n*16 + (lane&15), row = i*16 + (lane>>4)*4 + r
#pragma unroll
    for (int i = 0; i < 2; ++i) {
#pragma unroll
        for (int r = 0; r < 4; ++r) {
            const int row = row0 + i * 16 + kseg * 4 + r;
            if (row < N_NODES) {
#pragma unroll
                for (int n = 0; n < 8; ++n)
                    H[(size_t)row * OUT_DIM + n * 16 + rlo] = f2bf(acc[i][n][r]);
            }
        }
    }
}

// ---------------- 3-phase parallel scan, 25 blocks x 4096 ------------------
#define SCAN_NBLK 25
__global__ __launch_bounds__(1024) void scan_phase1(int* __restrict__ a, int n,
                                                    int* __restrict__ bsum) {
    __shared__ int wsum[16];
    const int tid = threadIdx.x, lane = tid & 63, wid = tid >> 6;
    const int base = blockIdx.x * 4096 + tid * 4;
    int e0 = (base + 0 < n) ? a[base + 0] : 0;
    int e1 = (base + 1 < n) ? a[base + 1] : 0;
    int e2 = (base + 2 < n) ? a[base + 2] : 0;
    int e3 = (base + 3 < n) ? a[base + 3] : 0;
    const int p0 = e0, p1 = p0 + e1, p2 = p1 + e2, p3 = p2 + e3;
    const int ts = p3;
    int sv = ts;
#pragma unroll
    for (int d = 1; d < 64; d <<= 1) {
        const int t = __shfl_up(sv, d, 64);
        if (lane >= d) sv += t;
    }
    if (lane == 63) wsum[wid] = sv;
    __syncthreads();
    if (wid == 0 && lane < 16) {
        int w = wsum[lane];
#pragma unroll
        for (int d = 1; d < 16; d <<= 1) {
            const int t = __shfl_up(w, d, 64);
            if (lane >= d) w += t;
        }
        wsum[lane] = w;
    }
    __syncthreads();
    const int wexcl = (wid > 0) ? wsum[wid - 1] : 0;
    const int texcl = (sv - ts) + wexcl;
    if (base + 0 < n) a[base + 0] = texcl + p0;
    if (base + 1 < n) a[base + 1] = texcl + p1;
    if (base + 2 < n) a[base + 2] = texcl + p2;
    if (base + 3 < n) a[base + 3] = texcl + p3;
    if (tid == 0) bsum[blockIdx.x] = wsum[15];
}

__global__ __launch_bounds__(64) void scan_phase2(int* __restrict__ bsum, int nb) {
    const int lane = threadIdx.x;
    const int v = (lane < nb) ? bsum[lane] : 0;
    int sv = v;
#pragma unroll
    for (int d = 1; d < 64; d <<= 1) {
        const int t = __shfl_up(sv, d, 64);
        if (lane >= d) sv += t;
    }
    if (lane < nb) bsum[lane] = sv - v;    // exclusive
}

__global__ __launch_bounds__(1024) void scan_phase3(int* __restrict__ a, int n,
                                                    const int* __restrict__ bsum,
                                                    int* __restrict__ cursor) {
    const int base = blockIdx.x * 4096 + threadIdx.x * 4;
    const int add  = bsum[blockIdx.x];
#pragma unroll
    for (int j = 0; j < 4; ++j) {
        const int i = base + j;
        if (i < n) {
            const int v = a[i] + add;
            a[i] = v;
            if (i < N_NODES) cursor[i] = v;
        }
    }
}

// ---------------- CSR build: scatter 8B (src,val) records ------------------
__global__ __launch_bounds__(256) void build_csr(const int* __restrict__ esrc,
                                                 const int* __restrict__ edst,
                                                 const float* __restrict__ eval,
                                                 int* __restrict__ cursor,
                                                 int2* __restrict__ recs) {
    const int e = blockIdx.x * 256 + threadIdx.x;
    if (e < N_EDGES) {
        const int d = edst[e];
        const int p = atomicAdd(&cursor[d], 1);
        int2 rec;
        rec.x = esrc[e];
        rec.y = __float_as_int(eval[e]);
        recs[p] = rec;
    }
}

// ---------------- SpMM pull (bf16 H): one wave per dst node, ReLU fused ----
__global__ __launch_bounds__(256) void spmm_pull(const ushort* __restrict__ H,
                                                 const int* __restrict__ offsets,
                                                 const int2* __restrict__ recs,
                                                 float* __restrict__ out) {
    const int node = (blockIdx.x * 256 + threadIdx.x) >> 6;
    const int lane = threadIdx.x & 63;
    if (node >= N_NODES) return;

    const int beg = offsets[node];
    const int end = offsets[node + 1];

    float ax = 0.0f, ay = 0.0f;
    int e = beg;
    for (; e + 3 < end; e += 4) {                    // 4-edge unroll for MLP
        const int2 r0 = recs[e + 0];
        const int2 r1 = recs[e + 1];
        const int2 r2 = recs[e + 2];
        const int2 r3 = recs[e + 3];
        const unsigned h0 = *(const unsigned*)(H + (size_t)r0.x * OUT_DIM + lane * 2);
        const unsigned h1 = *(const unsigned*)(H + (size_t)r1.x * OUT_DIM + lane * 2);
        const unsigned h2 = *(const unsigned*)(H + (size_t)r2.x * OUT_DIM + lane * 2);
        const unsigned h3 = *(const unsigned*)(H + (size_t)r3.x * OUT_DIM + lane * 2);
        const float v0 = __int_as_float(r0.y), v1 = __int_as_float(r1.y);
        const float v2 = __int_as_float(r2.y), v3 = __int_as_float(r3.y);
        ax = fmaf(v0, bflo(h0), ax);  ay = fmaf(v0, bfhi(h0), ay);
        ax = fmaf(v1, bflo(h1), ax);  ay = fmaf(v1, bfhi(h1), ay);
        ax = fmaf(v2, bflo(h2), ax);  ay = fmaf(v2, bfhi(h2), ay);
        ax = fmaf(v3, bflo(h3), ax);  ay = fmaf(v3, bfhi(h3), ay);
    }
    for (; e < end; ++e) {
        const int2 r0 = recs[e];
        const float v0 = __int_as_float(r0.y);
        const unsigned h0 = *(const unsigned*)(H + (size_t)r0.x * OUT_DIM + lane * 2);
        ax = fmaf(v0, bflo(h0), ax);  ay = fmaf(v0, bfhi(h0), ay);
    }

    float2 r;
    r.x = fmaxf(ax, 0.0f);
    r.y = fmaxf(ay, 0.0f);
    *reinterpret_cast<float2*>(out + (size_t)node * OUT_DIM + lane * 2) = r;
}

extern "C" void kernel_launch(void* const* d_in, const int* in_sizes, int n_in,
                              void* d_out, int out_size, void* d_ws, size_t ws_size,
                              hipStream_t stream) {
    const float* X    = (const float*)d_in[0];   // [N_NODES, IN_DIM]
    const float* W    = (const float*)d_in[1];   // [IN_DIM, OUT_DIM]
    const int*   esrc = (const int*)d_in[2];     // [N_EDGES]
    const int*   edst = (const int*)d_in[3];     // [N_EDGES]
    const float* eval = (const float*)d_in[4];   // [N_EDGES]
    float*       out  = (float*)d_out;           // [N_NODES, OUT_DIM]

    // Workspace layout (~39.3 MB)
    char* ws = (char*)d_ws;
    ushort* Hb     = (ushort*)ws;  ws += (size_t)N_NODES * OUT_DIM * sizeof(ushort);   // 25.6 MB
    ushort* Wp     = (ushort*)ws;  ws += (size_t)4096 * 8 * sizeof(ushort);            // 64 KB
    int*    offsets= (int*)ws;     ws += (((size_t)(N_NODES + 1) * 4 + 127) & ~(size_t)127);
    int*    bsum   = (int*)ws;     ws += 128;
    int*    cursor = (int*)ws;     ws += (((size_t)N_NODES * 4 + 127) & ~(size_t)127);
    int2*   recs   = (int2*)ws;    // 12.8 MB

    // 1) Pack W, then fused [GEMM || dst-histogram]
    pack_w<<<16, 256, 0, stream>>>(W, Wp);
    hipMemsetAsync(offsets, 0, (size_t)(N_NODES + 1) * sizeof(int), stream);
    gemm_hist<<<GEMM_BLOCKS + HIST_BLOCKS, 256, 0, stream>>>(X, (const bf16x8*)Wp, Hb,
                                                             edst, offsets);

    // 2) Scan + CSR build
    scan_phase1<<<SCAN_NBLK, 1024, 0, stream>>>(offsets, N_NODES + 1, bsum);
    scan_phase2<<<1, 64, 0, stream>>>(bsum, SCAN_NBLK);
    scan_phase3<<<SCAN_NBLK, 1024, 0, stream>>>(offsets, N_NODES + 1, bsum, cursor);
    build_csr<<<(N_EDGES + 255) / 256, 256, 0, stream>>>(esrc, edst, eval, cursor, recs);

    // 3) Pull-SpMM + ReLU, one wave per node
    spmm_pull<<<(N_NODES * 64 + 255) / 256, 256, 0, stream>>>(Hb, offsets, recs, out);
}

// Round 5
// 249.485 us; speedup vs baseline: 12.4831x; 1.1511x over previous
//
#include <hip/hip_runtime.h>
#include <hip/hip_bf16.h>

#define N_NODES 100000
#define N_EDGES 1600000
#define IN_DIM  256
#define OUT_DIM 128

#define GEMM_BLOCKS ((N_NODES + 127) / 128)        // 782
#define HIST_BLOCKS (N_EDGES / 256)                // 6250

#define NBUCK   196                                // ceil(100000 / 512)
#define BSHIFT  9                                  // 512 nodes per bucket
#define EPB     8192                               // edges per bin_coarse block
#define BIN_BLOCKS ((N_EDGES + EPB - 1) / EPB)     // 196

typedef __attribute__((ext_vector_type(8))) short bf16x8;
typedef __attribute__((ext_vector_type(4))) float f32x4;

__device__ __forceinline__ ushort f2bf(float f) {
    union { float f; unsigned u; } v; v.f = f;
    unsigned r = v.u + 0x7FFF + ((v.u >> 16) & 1);   // RNE
    return (ushort)(r >> 16);
}
__device__ __forceinline__ float bflo(unsigned u) {
    union { unsigned u; float f; } v; v.u = u << 16; return v.f;
}
__device__ __forceinline__ float bfhi(unsigned u) {
    union { unsigned u; float f; } v; v.u = u & 0xFFFF0000u; return v.f;
}

// ---------------- Pack W[256,128] f32 -> bf16 fragment-major ---------------
__global__ __launch_bounds__(256) void pack_w(const float* __restrict__ W,
                                              ushort* __restrict__ Wp) {
    const int t = blockIdx.x * 256 + threadIdx.x;
    if (t >= 4096) return;
    const int kk = t >> 9, n = (t >> 6) & 7, l = t & 63;
    const int kbase = kk * 32 + (l >> 4) * 8;
    const int col   = n * 16 + (l & 15);
    ushort* o = Wp + (size_t)t * 8;
#pragma unroll
    for (int j = 0; j < 8; ++j)
        o[j] = f2bf(W[(size_t)(kbase + j) * OUT_DIM + col]);
}

// ---------------- Fused: MFMA GEMM + node-level dst histogram --------------
__global__ __launch_bounds__(256) void gemm_hist(const float* __restrict__ X,
                                                 const bf16x8* __restrict__ Bp,
                                                 ushort* __restrict__ H,
                                                 const int* __restrict__ edst,
                                                 int* __restrict__ offsets) {
    if (blockIdx.x >= GEMM_BLOCKS) {
        const int i = (blockIdx.x - GEMM_BLOCKS) * 256 + threadIdx.x;
        if (i < N_EDGES) atomicAdd(&offsets[edst[i] + 1], 1);
        return;
    }

    const int lane = threadIdx.x & 63;
    const int wid  = threadIdx.x >> 6;
    const int row0 = blockIdx.x * 128 + wid * 32;
    const int rlo  = lane & 15;
    const int kseg = lane >> 4;

    f32x4 acc[2][8] = {};

    int ra = row0 + rlo;       if (ra >= N_NODES) ra = N_NODES - 1;
    int rb = row0 + 16 + rlo;  if (rb >= N_NODES) rb = N_NODES - 1;
    const float* pa = X + (size_t)ra * IN_DIM + kseg * 8;
    const float* pb = X + (size_t)rb * IN_DIM + kseg * 8;

    for (int kk = 0; kk < 8; ++kk) {
        const float4 a0lo = *(const float4*)(pa + kk * 32);
        const float4 a0hi = *(const float4*)(pa + kk * 32 + 4);
        const float4 a1lo = *(const float4*)(pb + kk * 32);
        const float4 a1hi = *(const float4*)(pb + kk * 32 + 4);
        bf16x8 A0, A1;
        A0[0]=f2bf(a0lo.x); A0[1]=f2bf(a0lo.y); A0[2]=f2bf(a0lo.z); A0[3]=f2bf(a0lo.w);
        A0[4]=f2bf(a0hi.x); A0[5]=f2bf(a0hi.y); A0[6]=f2bf(a0hi.z); A0[7]=f2bf(a0hi.w);
        A1[0]=f2bf(a1lo.x); A1[1]=f2bf(a1lo.y); A1[2]=f2bf(a1lo.z); A1[3]=f2bf(a1lo.w);
        A1[4]=f2bf(a1hi.x); A1[5]=f2bf(a1hi.y); A1[6]=f2bf(a1hi.z); A1[7]=f2bf(a1hi.w);

        const bf16x8* bbase = Bp + (size_t)(kk * 8) * 64 + lane;
#pragma unroll
        for (int n = 0; n < 8; ++n) {
            const bf16x8 Bf = bbase[(size_t)n * 64];
            acc[0][n] = __builtin_amdgcn_mfma_f32_16x16x32_bf16(A0, Bf, acc[0][n], 0, 0, 0);
            acc[1][n] = __builtin_amdgcn_mfma_f32_16x16x32_bf16(A1, Bf, acc[1][n], 0, 0, 0);
        }
    }

#pragma unroll
    for (int i = 0; i < 2; ++i) {
#pragma unroll
        for (int r = 0; r < 4; ++r) {
            const int row = row0 + i * 16 + kseg * 4 + r;
            if (row < N_NODES) {
#pragma unroll
                for (int n = 0; n < 8; ++n)
                    H[(size_t)row * OUT_DIM + n * 16 + rlo] = f2bf(acc[i][n][r]);
            }
        }
    }
}

// ---------------- 3-phase parallel scan, 25 blocks x 4096 ------------------
#define SCAN_NBLK 25
__global__ __launch_bounds__(1024) void scan_phase1(int* __restrict__ a, int n,
                                                    int* __restrict__ bsum) {
    __shared__ int wsum[16];
    const int tid = threadIdx.x, lane = tid & 63, wid = tid >> 6;
    const int base = blockIdx.x * 4096 + tid * 4;
    int e0 = (base + 0 < n) ? a[base + 0] : 0;
    int e1 = (base + 1 < n) ? a[base + 1] : 0;
    int e2 = (base + 2 < n) ? a[base + 2] : 0;
    int e3 = (base + 3 < n) ? a[base + 3] : 0;
    const int p0 = e0, p1 = p0 + e1, p2 = p1 + e2, p3 = p2 + e3;
    const int ts = p3;
    int sv = ts;
#pragma unroll
    for (int d = 1; d < 64; d <<= 1) {
        const int t = __shfl_up(sv, d, 64);
        if (lane >= d) sv += t;
    }
    if (lane == 63) wsum[wid] = sv;
    __syncthreads();
    if (wid == 0 && lane < 16) {
        int w = wsum[lane];
#pragma unroll
        for (int d = 1; d < 16; d <<= 1) {
            const int t = __shfl_up(w, d, 64);
            if (lane >= d) w += t;
        }
        wsum[lane] = w;
    }
    __syncthreads();
    const int wexcl = (wid > 0) ? wsum[wid - 1] : 0;
    const int texcl = (sv - ts) + wexcl;
    if (base + 0 < n) a[base + 0] = texcl + p0;
    if (base + 1 < n) a[base + 1] = texcl + p1;
    if (base + 2 < n) a[base + 2] = texcl + p2;
    if (base + 3 < n) a[base + 3] = texcl + p3;
    if (tid == 0) bsum[blockIdx.x] = wsum[15];
}

__global__ __launch_bounds__(64) void scan_phase2(int* __restrict__ bsum, int nb) {
    const int lane = threadIdx.x;
    const int v = (lane < nb) ? bsum[lane] : 0;
    int sv = v;
#pragma unroll
    for (int d = 1; d < 64; d <<= 1) {
        const int t = __shfl_up(sv, d, 64);
        if (lane >= d) sv += t;
    }
    if (lane < nb) bsum[lane] = sv - v;    // exclusive
}

// phase3 also seeds the per-node cursor and the 196 bucket cursors
__global__ __launch_bounds__(1024) void scan_phase3(int* __restrict__ a, int n,
                                                    const int* __restrict__ bsum,
                                                    int* __restrict__ cursor,
                                                    int* __restrict__ bcur) {
    const int base = blockIdx.x * 4096 + threadIdx.x * 4;
    const int add  = bsum[blockIdx.x];
#pragma unroll
    for (int j = 0; j < 4; ++j) {
        const int i = base + j;
        if (i < n) {
            const int v = a[i] + add;
            a[i] = v;
            if (i < N_NODES) {
                cursor[i] = v;
                if ((i & 511) == 0) bcur[i >> BSHIFT] = v;
            }
        }
    }
}

// ---------------- Pass 1: coarse bin into 196 dst-buckets ------------------
// Records packed: x = src | (dst&511)<<20 ; y = val bits
__global__ __launch_bounds__(256) void bin_coarse(const int* __restrict__ esrc,
                                                  const int* __restrict__ edst,
                                                  const float* __restrict__ eval,
                                                  int* __restrict__ bcur,
                                                  int2* __restrict__ binned) {
    __shared__ int cnt[NBUCK];
    __shared__ int sbase[NBUCK];
    const int tid = threadIdx.x;
    const int cb  = blockIdx.x * EPB;
    const int lim = (N_EDGES - cb < EPB) ? (N_EDGES - cb) : EPB;

    for (int b = tid; b < NBUCK; b += 256) cnt[b] = 0;
    __syncthreads();

    for (int i = tid; i < lim; i += 256) {
        const int b = edst[cb + i] >> BSHIFT;
        atomicAdd(&cnt[b], 1);
    }
    __syncthreads();

    if (tid < NBUCK) {
        const int c = cnt[tid];
        sbase[tid] = c ? atomicAdd(&bcur[tid], c) : 0;
        cnt[tid] = 0;
    }
    __syncthreads();

    for (int i = tid; i < lim; i += 256) {
        const int d = edst[cb + i];
        const int b = d >> BSHIFT;
        const int pos = sbase[b] + atomicAdd(&cnt[b], 1);
        int2 rec;
        rec.x = esrc[cb + i] | ((d & 511) << 20);
        rec.y = __float_as_int(eval[cb + i]);
        binned[pos] = rec;
    }
}

// ---------------- Pass 2: fine scatter within bucket (L2-local) ------------
__global__ __launch_bounds__(256) void bin_fine(const int* __restrict__ offsets,
                                                const int2* __restrict__ binned,
                                                int* __restrict__ cursor,
                                                int2* __restrict__ recs) {
    const int b = blockIdx.x;
    const int node0 = b << BSHIFT;
    int node1 = node0 + 512; if (node1 > N_NODES) node1 = N_NODES;
    const int beg = offsets[node0];
    const int end = offsets[node1];

    for (int k = beg + (int)threadIdx.x; k < end; k += 256) {
        const int2 rec = binned[k];
        const int dst = node0 + ((rec.x >> 20) & 511);
        const int src = rec.x & 0xFFFFF;
        const int pos = atomicAdd(&cursor[dst], 1);
        int2 o; o.x = src; o.y = rec.y;
        recs[pos] = o;
    }
}

// ---------------- SpMM pull (bf16 H): one wave per dst node, ReLU fused ----
__global__ __launch_bounds__(256) void spmm_pull(const ushort* __restrict__ H,
                                                 const int* __restrict__ offsets,
                                                 const int2* __restrict__ recs,
                                                 float* __restrict__ out) {
    const int node = (blockIdx.x * 256 + threadIdx.x) >> 6;
    const int lane = threadIdx.x & 63;
    if (node >= N_NODES) return;

    const int beg = offsets[node];
    const int end = offsets[node + 1];

    float ax = 0.0f, ay = 0.0f;
    int e = beg;
    for (; e + 3 < end; e += 4) {
        const int2 r0 = recs[e + 0];
        const int2 r1 = recs[e + 1];
        const int2 r2 = recs[e + 2];
        const int2 r3 = recs[e + 3];
        const unsigned h0 = *(const unsigned*)(H + (size_t)r0.x * OUT_DIM + lane * 2);
        const unsigned h1 = *(const unsigned*)(H + (size_t)r1.x * OUT_DIM + lane * 2);
        const unsigned h2 = *(const unsigned*)(H + (size_t)r2.x * OUT_DIM + lane * 2);
        const unsigned h3 = *(const unsigned*)(H + (size_t)r3.x * OUT_DIM + lane * 2);
        const float v0 = __int_as_float(r0.y), v1 = __int_as_float(r1.y);
        const float v2 = __int_as_float(r2.y), v3 = __int_as_float(r3.y);
        ax = fmaf(v0, bflo(h0), ax);  ay = fmaf(v0, bfhi(h0), ay);
        ax = fmaf(v1, bflo(h1), ax);  ay = fmaf(v1, bfhi(h1), ay);
        ax = fmaf(v2, bflo(h2), ax);  ay = fmaf(v2, bfhi(h2), ay);
        ax = fmaf(v3, bflo(h3), ax);  ay = fmaf(v3, bfhi(h3), ay);
    }
    for (; e < end; ++e) {
        const int2 r0 = recs[e];
        const float v0 = __int_as_float(r0.y);
        const unsigned h0 = *(const unsigned*)(H + (size_t)r0.x * OUT_DIM + lane * 2);
        ax = fmaf(v0, bflo(h0), ax);  ay = fmaf(v0, bfhi(h0), ay);
    }

    float2 r;
    r.x = fmaxf(ax, 0.0f);
    r.y = fmaxf(ay, 0.0f);
    *reinterpret_cast<float2*>(out + (size_t)node * OUT_DIM + lane * 2) = r;
}

extern "C" void kernel_launch(void* const* d_in, const int* in_sizes, int n_in,
                              void* d_out, int out_size, void* d_ws, size_t ws_size,
                              hipStream_t stream) {
    const float* X    = (const float*)d_in[0];   // [N_NODES, IN_DIM]
    const float* W    = (const float*)d_in[1];   // [IN_DIM, OUT_DIM]
    const int*   esrc = (const int*)d_in[2];     // [N_EDGES]
    const int*   edst = (const int*)d_in[3];     // [N_EDGES]
    const float* eval = (const float*)d_in[4];   // [N_EDGES]
    float*       out  = (float*)d_out;           // [N_NODES, OUT_DIM]

    // Workspace layout (~52 MB)
    char* ws = (char*)d_ws;
    ushort* Hb     = (ushort*)ws;  ws += (size_t)N_NODES * OUT_DIM * sizeof(ushort);   // 25.6 MB
    ushort* Wp     = (ushort*)ws;  ws += (size_t)4096 * 8 * sizeof(ushort);            // 64 KB
    int*    offsets= (int*)ws;     ws += (((size_t)(N_NODES + 1) * 4 + 127) & ~(size_t)127);
    int*    bsum   = (int*)ws;     ws += 128;
    int*    cursor = (int*)ws;     ws += (((size_t)N_NODES * 4 + 127) & ~(size_t)127);
    int*    bcur   = (int*)ws;     ws += ((NBUCK * 4 + 127) & ~127);
    int2*   binned = (int2*)ws;    ws += (size_t)N_EDGES * sizeof(int2);               // 12.8 MB
    int2*   recs   = (int2*)ws;    // 12.8 MB

    // 1) Pack W, then fused [GEMM || node-level dst-histogram]
    pack_w<<<16, 256, 0, stream>>>(W, Wp);
    hipMemsetAsync(offsets, 0, (size_t)(N_NODES + 1) * sizeof(int), stream);
    gemm_hist<<<GEMM_BLOCKS + HIST_BLOCKS, 256, 0, stream>>>(X, (const bf16x8*)Wp, Hb,
                                                             edst, offsets);

    // 2) Scan (also seeds node cursors + bucket cursors)
    scan_phase1<<<SCAN_NBLK, 1024, 0, stream>>>(offsets, N_NODES + 1, bsum);
    scan_phase2<<<1, 64, 0, stream>>>(bsum, SCAN_NBLK);
    scan_phase3<<<SCAN_NBLK, 1024, 0, stream>>>(offsets, N_NODES + 1, bsum, cursor, bcur);

    // 3) Two-pass dst-binning (coarse buckets -> exact CSR positions)
    bin_coarse<<<BIN_BLOCKS, 256, 0, stream>>>(esrc, edst, eval, bcur, binned);
    bin_fine<<<NBUCK, 256, 0, stream>>>(offsets, binned, cursor, recs);

    // 4) Pull-SpMM + ReLU, one wave per node
    spmm_pull<<<(N_NODES * 64 + 255) / 256, 256, 0, stream>>>(Hb, offsets, recs, out);
}